// Round 18
// baseline (96.482 us; speedup 1.0000x reference)
//
#include <hip/hip_runtime.h>
#include <hip/hip_fp16.h>
#include <math.h>

#define NQ    14
#define DIM   16384
#define DEPTH 4

typedef __attribute__((ext_vector_type(2))) float f2;
typedef __attribute__((ext_vector_type(4))) float f4;

__device__ __forceinline__ f2 cmul(f2 a, f2 b) {
    return (f2){a.x*b.x - a.y*b.y, a.x*b.y + a.y*b.x};
}
__device__ __forceinline__ float czsgn(int e) {
    return (__popc(e & (e >> 1)) & 1) ? -1.0f : 1.0f;
}

// ---------------- forced packed-f16 math ----------------
// r15 (bench 91.9, absmax 0.0156) halved the nominal f16 instruction count but
// moved the wall only ~3us; r17's native _Float16 was worse (63us profiled).
// Theory: __hfma2 never lowered to v_pk_fma_f16 (paired scalar v_fma_f16 =
// same cycles as pk_f32). Decisive test: emit the instruction via inline asm.
// Negations are folded into the gate table (store -imag), so every butterfly
// is a clean fma/mul chain with no modifiers — same association as r15's
// chain, so results are bitwise identical.
__device__ __forceinline__ int pkfma(int a, int b, int c) {
    int d;
    asm("v_pk_fma_f16 %0, %1, %2, %3" : "=v"(d) : "v"(a), "v"(b), "v"(c));
    return d;
}
__device__ __forceinline__ int pkmul(int a, int b) {
    int d;
    asm("v_pk_mul_f16 %0, %1, %2" : "=v"(d) : "v"(a), "v"(b));
    return d;
}

// complex butterfly on packed planes: out = c1*x + c2*y
// consts: c1r, c1i, n1=-c1i, c2r, c2i, n2=-c2i
__device__ __forceinline__ void cfma2(int c1r, int c1i, int n1,
                                      int c2r, int c2i, int n2,
                                      int xr, int xi, int yr, int yi,
                                      int& or_, int& oi_)
{
    or_ = pkfma(c1r, xr, pkfma(n1,  xi, pkfma(c2r, yr, pkmul(n2,  yi))));
    oi_ = pkfma(c1r, xi, pkfma(c1i, xr, pkfma(c2r, yi, pkmul(c2i, yr))));
}

template<int CTRL>
__device__ __forceinline__ int dppi(int v) {
    return __builtin_amdgcn_update_dpp(0, v, CTRL, 0xF, 0xF, true);
}
template<int XB> __device__ __forceinline__ int lxi(int v);
template<> __device__ __forceinline__ int lxi<1>(int v) { return dppi<0xB1>(v); }   // quad_perm [1,0,3,2]
template<> __device__ __forceinline__ int lxi<2>(int v) { return dppi<0x4E>(v); }   // quad_perm [2,3,0,1]
template<> __device__ __forceinline__ int lxi<8>(int v) { return dppi<0x128>(v); }  // row_ror:8 == xor8

// gate slot layout (12 ints): [0..5] = row0 {u00r,u00i,-u00i,u01r,u01i,-u01i}
//                             [6..11] = row1 {u10r,u10i,-u10i,u11r,u11i,-u11i}
// (pair gate uses only [0..5] with column-packed A/B.)

// reg gate, cross-pair (pair-index mask KM in {4,2,1} <-> l-mask {8,4,2})
template<int KM>
__device__ __forceinline__ void reg_gate_h(int hr[8], int hi[8], const int* __restrict__ g) {
    int a0 = g[0], a1 = g[1], a2 = g[2], a3 = g[3], a4 = g[4], a5 = g[5];
    int b0 = g[6], b1 = g[7], b2 = g[8], b3 = g[9], b4 = g[10], b5 = g[11];
    #pragma unroll
    for (int k = 0; k < 8; ++k) {
        if (k & KM) continue;
        const int j = k | KM;
        int xr = hr[k], xi = hi[k], yr = hr[j], yi = hi[j];
        cfma2(a0, a1, a2, a3, a4, a5, xr, xi, yr, yi, hr[k], hi[k]);
        cfma2(b0, b1, b2, b3, b4, b5, xr, xi, yr, yi, hr[j], hi[j]);
    }
}

// within-pair gate (l-mask 1): partner = swapped halves (v_alignbit rotate)
__device__ __forceinline__ int hswap(int v) {
    return (v << 16) | ((unsigned)v >> 16);
}
__device__ __forceinline__ void pair_gate_h(int hr[8], int hi[8], const int* __restrict__ g) {
    int a0 = g[0], a1 = g[1], a2 = g[2], a3 = g[3], a4 = g[4], a5 = g[5];
    #pragma unroll
    for (int k = 0; k < 8; ++k) {
        int pr = hswap(hr[k]);
        int pi = hswap(hi[k]);
        cfma2(a0, a1, a2, a3, a4, a5, hr[k], hi[k], pr, pi, hr[k], hi[k]);
    }
}

// lane gate: DPP partner; per-lane row select
// lo: c1=u00 c2=u01 -> g[0..5]; hi: c1=u11 c2=u10 -> {g9,g10,g11,g6,g7,g8}
template<int XB>
__device__ __forceinline__ void lane_gate_h(int hr[8], int hi[8], const int* __restrict__ g, int t) {
    const bool h = (t & XB) != 0;
    int c1r = h ? g[9]  : g[0];
    int c1i = h ? g[10] : g[1];
    int n1  = h ? g[11] : g[2];
    int c2r = h ? g[6]  : g[3];
    int c2i = h ? g[7]  : g[4];
    int n2  = h ? g[8]  : g[5];
    #pragma unroll
    for (int k = 0; k < 8; ++k) {
        int pr = lxi<XB>(hr[k]);
        int pi = lxi<XB>(hi[k]);
        cfma2(c1r, c1i, n1, c2r, c2i, n2, hr[k], hi[k], pr, pi, hr[k], hi[k]);
    }
}

// CZ signs as sign-bit XOR. View A: e=(l<<10)|(n<<4)|w (HW-verified r10/r15).
__device__ __forceinline__ void cz_A_h(int hr[8], int hi[8], int t) {
    const int n = t & 63, w = t >> 6;
    const int pT = (__popc(w & (w >> 1)) + __popc(n & (n >> 1)) + ((n & 1) & (w >> 3))) & 1;
    const int f0 = pT, f1 = pT ^ ((n >> 5) & 1);   // F1: cross term l0 & n5
    #pragma unroll
    for (int k = 0; k < 8; ++k) {
        const int stlo = __popc((2*k) & ((2*k) >> 1)) & 1;
        const int sthi = __popc((2*k+1) & ((2*k+1) >> 1)) & 1;
        const int mask = ((f0 ^ stlo) ? 0x8000 : 0)
                       | ((f1 ^ sthi) ? 0x80000000 : 0);
        hr[k] ^= mask; hi[k] ^= mask;
    }
}
// View B: e9=n3,e8=n1,e7=n5,e6=n0,e5=n4,e4=n2 (HW-verified); cross = l3&n2.
__device__ __forceinline__ void cz_B_h(int hr[8], int hi[8], int t) {
    const int n = t & 63, w = t >> 6;
    const int n0 = n & 1, n1 = (n >> 1) & 1, n2 = (n >> 2) & 1;
    const int n3 = (n >> 3) & 1, n4 = (n >> 4) & 1, n5 = (n >> 5) & 1;
    const int pT = ((n2 & n4) ^ (n4 & n0) ^ (n0 & n5) ^ (n5 & n1) ^ (n1 & n3)
                    ^ (n3 & (w & 1)) ^ (__popc(w & (w >> 1)) & 1));
    const int f0 = pT, f1 = pT ^ n2;
    #pragma unroll
    for (int k = 0; k < 8; ++k) {
        const int fs = (k & 4) ? f1 : f0;           // l3 = k&4 selects F
        const int stlo = __popc((2*k) & ((2*k) >> 1)) & 1;
        const int sthi = __popc((2*k+1) & ((2*k+1) >> 1)) & 1;
        const int mask = ((fs ^ stlo) ? 0x8000 : 0)
                       | ((fs ^ sthi) ? 0x80000000 : 0);
        hr[k] ^= mask; hi[k] ^= mask;
    }
}

__device__ __forceinline__ int packh2(float a, float b) {
    union { __half2 h; int i; } u;
    u.h = __floats2half2_rn(a, b);
    return u.i;
}

// ---- prep: gates -> d_ws (batch-invariant; 1 block) ----
// int table: 6 half-layers x 7 slots x 12 ints; layer-0 fp32 gates after.
__global__ void qlg_prep(const float* __restrict__ wts, int* __restrict__ Gh,
                         f4* __restrict__ G0)
{
    const int t = threadIdx.x;
    if (t >= DEPTH * NQ) return;
    const int d = t / NQ, ww = t % NQ;
    const float p0 = wts[(d*NQ + ww)*3 + 0];
    const float p1 = wts[(d*NQ + ww)*3 + 1];
    const float p2 = wts[(d*NQ + ww)*3 + 2];
    float s0, c0, s1, c1, s2, c2;
    sincosf(0.5f*p0, &s0, &c0);
    sincosf(0.5f*p1, &s1, &c1);
    sincosf(0.5f*p2, &s2, &c2);
    // U = RY(p2) * RX(p1) * RZ(p0)
    f2 e0  = (f2){c0, -s0};
    f2 e0c = (f2){c0,  s0};
    f2 is1 = (f2){0.f, -s1};
    f2 m00 = c1 * e0;
    f2 m01 = cmul(is1, e0c);
    f2 m10 = cmul(is1, e0);
    f2 m11 = c1 * e0c;
    f2 u00 = c2*m00 - s2*m10;
    f2 u01 = c2*m01 - s2*m11;
    f2 u10 = s2*m00 + c2*m10;
    f2 u11 = s2*m01 + c2*m11;
    if (d == 0) {
        G0[ww*2 + 0] = (f4){u00.x, u00.y, u01.x, u01.y};
        G0[ww*2 + 1] = (f4){u10.x, u10.y, u11.x, u11.y};
        return;
    }
    // half-layers h0..h5 = (1,A),(1,B),(2,B),(2,A),(3,A),(3,B);
    // slots: A: q0,q1,q2,q3,q6,q8,q9   B: q10,q11,q12,q13,q4,q5,q7
    const bool isA = (ww <= 3) || (ww == 6) || (ww == 8) || (ww == 9);
    int slot;
    if (isA) slot = (ww <= 3) ? ww : (ww == 6 ? 4 : (ww == 8 ? 5 : 6));
    else     slot = (ww >= 10) ? (ww - 10) : (ww == 4 ? 4 : (ww == 5 ? 5 : 6));
    const int h = (d == 1) ? (isA ? 0 : 1)
                : (d == 2) ? (isA ? 3 : 2)
                           : (isA ? 4 : 5);
    int* g = Gh + (h*7 + slot)*12;
    if (slot == 3) {   // within-pair gate: column packing A=(u00,u11) B=(u01,u10)
        g[0] = packh2(u00.x,  u11.x);
        g[1] = packh2(u00.y,  u11.y);
        g[2] = packh2(-u00.y, -u11.y);
        g[3] = packh2(u01.x,  u10.x);
        g[4] = packh2(u01.y,  u10.y);
        g[5] = packh2(-u01.y, -u10.y);
        #pragma unroll
        for (int k = 6; k < 12; ++k) g[k] = 0;
    } else {           // broadcast packing, rows with pre-negated imag
        g[0]  = packh2(u00.x,  u00.x);
        g[1]  = packh2(u00.y,  u00.y);
        g[2]  = packh2(-u00.y, -u00.y);
        g[3]  = packh2(u01.x,  u01.x);
        g[4]  = packh2(u01.y,  u01.y);
        g[5]  = packh2(-u01.y, -u01.y);
        g[6]  = packh2(u10.x,  u10.x);
        g[7]  = packh2(u10.y,  u10.y);
        g[8]  = packh2(-u10.y, -u10.y);
        g[9]  = packh2(u11.x,  u11.x);
        g[10] = packh2(u11.y,  u11.y);
        g[11] = packh2(-u11.y, -u11.y);
    }
}

__global__ __launch_bounds__(1024)
void qlg_kernel(const float* __restrict__ cond,
                const float* __restrict__ Wenc,
                const float* __restrict__ benc,
                const int* __restrict__ Gh,
                const f4* __restrict__ G0,
                float* __restrict__ out)
{
    __shared__ int st[DIM];                 // 64 KB remap buffer (packed f16 amps)
    __shared__ f2 qv[NQ][2];
    __shared__ f2 Phi[128];
    __shared__ f2 Plo[128];
    __shared__ float wred[16][NQ];
    __shared__ float lat[NQ];

    const int b = blockIdx.x;
    const int t = threadIdx.x;
    const int n = t & 63, w = t >> 6;
    const int bB = (w << 10)
                 | (((n >> 3) & 1) << 5) | (((n >> 1) & 1) << 4)
                 | (((n >> 5) & 1) << 3) | ((n & 1) << 2)
                 | (((n >> 4) & 1) << 1) | ((n >> 2) & 1);

    // ---- stage 1+2 merged: embedding (SiLU) + per-wire 2-vectors ----
    if (t < NQ) {
        float s = benc[t];
        #pragma unroll
        for (int k = 0; k < NQ; ++k) s += cond[b*NQ + k] * Wenc[t*NQ + k];
        float v = s / (1.0f + __expf(-s));
        float sn, cs;
        sincosf(0.5f*v, &sn, &cs);
        f2 a0 = (f2){cs*cs,  sn*sn};
        f2 a1 = (f2){sn*cs, -sn*cs};
        f4 va = G0[t*2], vb = G0[t*2 + 1];
        f2 u00 = (f2){va.x, va.y}, u01 = (f2){va.z, va.w};
        f2 u10 = (f2){vb.x, vb.y}, u11 = (f2){vb.z, vb.w};
        qv[t][0] = cmul(u00, a0) + cmul(u01, a1);
        qv[t][1] = cmul(u10, a0) + cmul(u11, a1);
    }
    __syncthreads();

    // ---- stage 3: partial-product tables (fp32) ----
    if (t < 128) {
        f2 p = qv[0][(t >> 6) & 1];
        #pragma unroll
        for (int ww = 1; ww <= 6; ++ww) p = cmul(p, qv[ww][(t >> (6 - ww)) & 1]);
        Phi[t] = p;
    } else if (t < 256) {
        const int j = t - 128;
        f2 p = qv[7][(j >> 6) & 1];
        #pragma unroll
        for (int ww = 8; ww <= 13; ++ww) p = cmul(p, qv[ww][(j >> (13 - ww)) & 1]);
        Plo[j] = p;
    }
    __syncthreads();

    // ---- stage 4: build product state in f16 planes (view A), CZ0 fused ----
    int hr[8], hi[8];
    {
        f2 plo = Plo[((n & 7) << 4) | w];
        #pragma unroll
        for (int k = 0; k < 8; ++k) {
            const int l0 = 2*k, l1 = 2*k + 1;
            const int e0 = (l0 << 10) | (n << 4) | w;
            const int e1 = (l1 << 10) | (n << 4) | w;
            f2 a0 = cmul(Phi[(l0 << 3) | (n >> 3)], plo) * czsgn(e0);
            f2 a1 = cmul(Phi[(l1 << 3) | (n >> 3)], plo) * czsgn(e1);
            hr[k] = packh2(a0.x, a1.x);
            hi[k] = packh2(a0.y, a1.y);
        }
    }

    // ---- stage 5: 6 half-layers ----
    #pragma unroll
    for (int h = 0; h < 6; ++h) {
        const int* __restrict__ g = Gh + h*7*12;
        reg_gate_h<4>(hr, hi, g + 0*12);    // l-mask 8
        reg_gate_h<2>(hr, hi, g + 1*12);    // l-mask 4
        reg_gate_h<1>(hr, hi, g + 2*12);    // l-mask 2
        pair_gate_h(hr, hi, g + 3*12);      // l-mask 1
        lane_gate_h<8>(hr, hi, g + 4*12, t);
        lane_gate_h<2>(hr, hi, g + 5*12, t);
        lane_gate_h<1>(hr, hi, g + 6*12, t);
        if (h == 1)      cz_B_h(hr, hi, t); // CZ after layer 1 (view B)
        else if (h == 3) cz_A_h(hr, hi, t); // CZ after layer 2 (view A)
        if (h == 0 || h == 4) {             // remap A -> B
            #pragma unroll
            for (int k = 0; k < 8; ++k) {
                st[t + ((2*k)   << 10)] = (hr[k] & 0xFFFF) | (hi[k] << 16);
                st[t + ((2*k+1) << 10)] = ((unsigned)hr[k] >> 16) | (hi[k] & 0xFFFF0000);
            }
            __syncthreads();
            #pragma unroll
            for (int k = 0; k < 8; ++k) {
                int w0 = st[bB + ((2*k)   << 6)];
                int w1 = st[bB + ((2*k+1) << 6)];
                hr[k] = (w0 & 0xFFFF) | (w1 << 16);
                hi[k] = ((unsigned)w0 >> 16) | (w1 & 0xFFFF0000);
            }
        } else if (h == 2) {                // remap B -> A
            #pragma unroll
            for (int k = 0; k < 8; ++k) {
                st[bB + ((2*k)   << 6)] = (hr[k] & 0xFFFF) | (hi[k] << 16);
                st[bB + ((2*k+1) << 6)] = ((unsigned)hr[k] >> 16) | (hi[k] & 0xFFFF0000);
            }
            __syncthreads();
            #pragma unroll
            for (int k = 0; k < 8; ++k) {
                int w0 = st[t + ((2*k)   << 10)];
                int w1 = st[t + ((2*k+1) << 10)];
                hr[k] = (w0 & 0xFFFF) | (w1 << 16);
                hi[k] = ((unsigned)w0 >> 16) | (w1 & 0xFFFF0000);
            }
        }
    }
    // (CZ after layer 3 dropped: |psi|^2 invariant)

    // ---- fused probability reduction (view B, fp32 accumulate) ----
    float SU, Q10, Q11, Q12, Q13;
    {
        SU = Q10 = Q11 = Q12 = Q13 = 0.f;
        #pragma unroll
        for (int k = 0; k < 8; ++k) {
            union { int i; __half2 h; } ur, ui;
            ur.i = hr[k]; ui.i = hi[k];
            float2 fr = __half22float2(ur.h);
            float2 fi = __half22float2(ui.h);
            float pl = fr.x*fr.x + fi.x*fi.x;
            float ph = fr.y*fr.y + fi.y*fi.y;
            float g2 = pl + ph;
            SU  += g2;
            Q13 += pl - ph;                 // l0
            Q10 += (k & 4) ? -g2 : g2;      // l3
            Q11 += (k & 2) ? -g2 : g2;      // l2
            Q12 += (k & 1) ? -g2 : g2;      // l1
        }
    }

    // ---- stage 6: reduce to 14 expectations, layernorm (fp32) ----
    // View-B thread-uniform sign bits: q0:t9 q1:t8 q2:t7 q3:t6 q4:t3 q5:t1
    // q6:t5 q7:t0 q8:t4 q9:t2.
    {
        const int lane = t & 63, wv = t >> 6;
        const int sbit[10] = {9, 8, 7, 6, 3, 1, 5, 0, 4, 2};
        #pragma unroll
        for (int ww = 0; ww < NQ; ++ww) {
            float v;
            if      (ww == 10) v = Q10;
            else if (ww == 11) v = Q11;
            else if (ww == 12) v = Q12;
            else if (ww == 13) v = Q13;
            else               v = ((t >> sbit[ww]) & 1) ? -SU : SU;
            #pragma unroll
            for (int off = 32; off > 0; off >>= 1) v += __shfl_down(v, off, 64);
            if (lane == 0) wred[wv][ww] = v;
        }
    }
    __syncthreads();
    if (t < NQ) {
        float s = 0.f;
        #pragma unroll
        for (int k = 0; k < 16; ++k) s += wred[k][t];
        lat[t] = s;
    }
    __syncthreads();
    if (t < NQ) {
        float mu = 0.f;
        #pragma unroll
        for (int k = 0; k < NQ; ++k) mu += lat[k];
        mu *= (1.0f / NQ);
        float var = 0.f;
        #pragma unroll
        for (int k = 0; k < NQ; ++k) { float dv = lat[k] - mu; var += dv*dv; }
        var *= (1.0f / NQ);
        out[b*NQ + t] = (lat[t] - mu) * rsqrtf(var + 1e-5f);
    }
}

extern "C" void kernel_launch(void* const* d_in, const int* in_sizes, int n_in,
                              void* d_out, int out_size, void* d_ws, size_t ws_size,
                              hipStream_t stream)
{
    (void)n_in; (void)ws_size; (void)out_size;
    const float* cond = (const float*)d_in[0];
    const float* Wenc = (const float*)d_in[1];
    const float* benc = (const float*)d_in[2];
    const float* wts  = (const float*)d_in[3];
    float* out = (float*)d_out;
    int* Gh = (int*)d_ws;                        // 504 ints = 2016 B
    f4* G0 = (f4*)((char*)d_ws + 4096);          // 28 f4 = 448 B
    const int B = in_sizes[0] / NQ;              // 256
    qlg_prep<<<dim3(1), dim3(64), 0, stream>>>(wts, Gh, G0);
    qlg_kernel<<<dim3(B), dim3(1024), 0, stream>>>(cond, Wenc, benc, Gh, G0, out);
}

// Round 19
// 94.323 us; speedup vs baseline: 1.0229x; 1.0229x over previous
//
#include <hip/hip_runtime.h>
#include <hip/hip_fp16.h>
#include <math.h>

#define NQ    14
#define DIM   16384
#define DEPTH 4

typedef __attribute__((ext_vector_type(2))) float f2;
typedef __attribute__((ext_vector_type(4))) float f4;

__device__ __forceinline__ f2 cmul(f2 a, f2 b) {
    return (f2){a.x*b.x - a.y*b.y, a.x*b.y + a.y*b.x};
}
__device__ __forceinline__ float czsgn(int e) {
    return (__popc(e & (e >> 1)) & 1) ? -1.0f : 1.0f;
}

// ---------------- forced packed-f16 math, gates in SGPRs ----------------
// r18 proved v_pk_fma_f16 emits fine but "v" constraints forced wave-uniform
// gate constants into VGPRs (vector loads + v_movs in the chain; VGPR=44,
// busy 60%). VOP3P takes ONE SGPR source — the gate slot. r19: reg/pair
// gates use "s" constraints (s_load -> SMEM pipe, hoisted, zero VALU/VGPR);
// lane gates keep "v" (per-lane row select via cndmask). Math byte-identical
// to r18 (absmax 0.015625 HW-verified).
__device__ __forceinline__ int pkfma_s(int g, int x, int acc) {
    int d;
    asm("v_pk_fma_f16 %0, %1, %2, %3" : "=v"(d) : "s"(g), "v"(x), "v"(acc));
    return d;
}
__device__ __forceinline__ int pkmul_s(int g, int x) {
    int d;
    asm("v_pk_mul_f16 %0, %1, %2" : "=v"(d) : "s"(g), "v"(x));
    return d;
}
__device__ __forceinline__ int pkfma_v(int g, int x, int acc) {
    int d;
    asm("v_pk_fma_f16 %0, %1, %2, %3" : "=v"(d) : "v"(g), "v"(x), "v"(acc));
    return d;
}
__device__ __forceinline__ int pkmul_v(int g, int x) {
    int d;
    asm("v_pk_mul_f16 %0, %1, %2" : "=v"(d) : "v"(g), "v"(x));
    return d;
}

// complex butterfly on packed planes: out = c1*x + c2*y
// consts: c1r, c1i, n1=-c1i, c2r, c2i, n2=-c2i  (negations pre-folded)
__device__ __forceinline__ void cfma2_s(int c1r, int c1i, int n1,
                                        int c2r, int c2i, int n2,
                                        int xr, int xi, int yr, int yi,
                                        int& or_, int& oi_)
{
    or_ = pkfma_s(c1r, xr, pkfma_s(n1,  xi, pkfma_s(c2r, yr, pkmul_s(n2,  yi))));
    oi_ = pkfma_s(c1r, xi, pkfma_s(c1i, xr, pkfma_s(c2r, yi, pkmul_s(c2i, yr))));
}
__device__ __forceinline__ void cfma2_v(int c1r, int c1i, int n1,
                                        int c2r, int c2i, int n2,
                                        int xr, int xi, int yr, int yi,
                                        int& or_, int& oi_)
{
    or_ = pkfma_v(c1r, xr, pkfma_v(n1,  xi, pkfma_v(c2r, yr, pkmul_v(n2,  yi))));
    oi_ = pkfma_v(c1r, xi, pkfma_v(c1i, xr, pkfma_v(c2r, yi, pkmul_v(c2i, yr))));
}

template<int CTRL>
__device__ __forceinline__ int dppi(int v) {
    return __builtin_amdgcn_update_dpp(0, v, CTRL, 0xF, 0xF, true);
}
template<int XB> __device__ __forceinline__ int lxi(int v);
template<> __device__ __forceinline__ int lxi<1>(int v) { return dppi<0xB1>(v); }   // quad_perm [1,0,3,2]
template<> __device__ __forceinline__ int lxi<2>(int v) { return dppi<0x4E>(v); }   // quad_perm [2,3,0,1]
template<> __device__ __forceinline__ int lxi<8>(int v) { return dppi<0x128>(v); }  // row_ror:8 == xor8

// gate slot layout (12 ints): [0..5] = row0 {u00r,u00i,-u00i,u01r,u01i,-u01i}
//                             [6..11] = row1 {u10r,u10i,-u10i,u11r,u11i,-u11i}

// reg gate, cross-pair (pair-index mask KM in {4,2,1} <-> l-mask {8,4,2})
template<int KM>
__device__ __forceinline__ void reg_gate_h(int hr[8], int hi[8], const int* __restrict__ g) {
    int a0 = g[0], a1 = g[1], a2 = g[2], a3 = g[3], a4 = g[4], a5 = g[5];
    int b0 = g[6], b1 = g[7], b2 = g[8], b3 = g[9], b4 = g[10], b5 = g[11];
    #pragma unroll
    for (int k = 0; k < 8; ++k) {
        if (k & KM) continue;
        const int j = k | KM;
        int xr = hr[k], xi = hi[k], yr = hr[j], yi = hi[j];
        cfma2_s(a0, a1, a2, a3, a4, a5, xr, xi, yr, yi, hr[k], hi[k]);
        cfma2_s(b0, b1, b2, b3, b4, b5, xr, xi, yr, yi, hr[j], hi[j]);
    }
}

// within-pair gate (l-mask 1): partner = swapped halves
__device__ __forceinline__ int hswap(int v) {
    return (v << 16) | ((unsigned)v >> 16);
}
__device__ __forceinline__ void pair_gate_h(int hr[8], int hi[8], const int* __restrict__ g) {
    int a0 = g[0], a1 = g[1], a2 = g[2], a3 = g[3], a4 = g[4], a5 = g[5];
    #pragma unroll
    for (int k = 0; k < 8; ++k) {
        int pr = hswap(hr[k]);
        int pi = hswap(hi[k]);
        cfma2_s(a0, a1, a2, a3, a4, a5, hr[k], hi[k], pr, pi, hr[k], hi[k]);
    }
}

// lane gate: DPP partner; per-lane row select (divergent -> VGPR operands)
// lo: c1=u00 c2=u01 -> g[0..5]; hi: c1=u11 c2=u10 -> {g9,g10,g11,g6,g7,g8}
template<int XB>
__device__ __forceinline__ void lane_gate_h(int hr[8], int hi[8], const int* __restrict__ g, int t) {
    const bool h = (t & XB) != 0;
    int c1r = h ? g[9]  : g[0];
    int c1i = h ? g[10] : g[1];
    int n1  = h ? g[11] : g[2];
    int c2r = h ? g[6]  : g[3];
    int c2i = h ? g[7]  : g[4];
    int n2  = h ? g[8]  : g[5];
    #pragma unroll
    for (int k = 0; k < 8; ++k) {
        int pr = lxi<XB>(hr[k]);
        int pi = lxi<XB>(hi[k]);
        cfma2_v(c1r, c1i, n1, c2r, c2i, n2, hr[k], hi[k], pr, pi, hr[k], hi[k]);
    }
}

// CZ signs as sign-bit XOR. View A: e=(l<<10)|(n<<4)|w (HW-verified r10/r15).
__device__ __forceinline__ void cz_A_h(int hr[8], int hi[8], int t) {
    const int n = t & 63, w = t >> 6;
    const int pT = (__popc(w & (w >> 1)) + __popc(n & (n >> 1)) + ((n & 1) & (w >> 3))) & 1;
    const int f0 = pT, f1 = pT ^ ((n >> 5) & 1);   // F1: cross term l0 & n5
    #pragma unroll
    for (int k = 0; k < 8; ++k) {
        const int stlo = __popc((2*k) & ((2*k) >> 1)) & 1;
        const int sthi = __popc((2*k+1) & ((2*k+1) >> 1)) & 1;
        const int mask = ((f0 ^ stlo) ? 0x8000 : 0)
                       | ((f1 ^ sthi) ? 0x80000000 : 0);
        hr[k] ^= mask; hi[k] ^= mask;
    }
}
// View B: e9=n3,e8=n1,e7=n5,e6=n0,e5=n4,e4=n2 (HW-verified); cross = l3&n2.
__device__ __forceinline__ void cz_B_h(int hr[8], int hi[8], int t) {
    const int n = t & 63, w = t >> 6;
    const int n0 = n & 1, n1 = (n >> 1) & 1, n2 = (n >> 2) & 1;
    const int n3 = (n >> 3) & 1, n4 = (n >> 4) & 1, n5 = (n >> 5) & 1;
    const int pT = ((n2 & n4) ^ (n4 & n0) ^ (n0 & n5) ^ (n5 & n1) ^ (n1 & n3)
                    ^ (n3 & (w & 1)) ^ (__popc(w & (w >> 1)) & 1));
    const int f0 = pT, f1 = pT ^ n2;
    #pragma unroll
    for (int k = 0; k < 8; ++k) {
        const int fs = (k & 4) ? f1 : f0;           // l3 = k&4 selects F
        const int stlo = __popc((2*k) & ((2*k) >> 1)) & 1;
        const int sthi = __popc((2*k+1) & ((2*k+1) >> 1)) & 1;
        const int mask = ((fs ^ stlo) ? 0x8000 : 0)
                       | ((fs ^ sthi) ? 0x80000000 : 0);
        hr[k] ^= mask; hi[k] ^= mask;
    }
}

__device__ __forceinline__ int packh2(float a, float b) {
    union { __half2 h; int i; } u;
    u.h = __floats2half2_rn(a, b);
    return u.i;
}

// ---- prep: gates -> d_ws (batch-invariant; 1 block) ----
// int table: 6 half-layers x 7 slots x 12 ints; layer-0 fp32 gates after.
__global__ void qlg_prep(const float* __restrict__ wts, int* __restrict__ Gh,
                         f4* __restrict__ G0)
{
    const int t = threadIdx.x;
    if (t >= DEPTH * NQ) return;
    const int d = t / NQ, ww = t % NQ;
    const float p0 = wts[(d*NQ + ww)*3 + 0];
    const float p1 = wts[(d*NQ + ww)*3 + 1];
    const float p2 = wts[(d*NQ + ww)*3 + 2];
    float s0, c0, s1, c1, s2, c2;
    sincosf(0.5f*p0, &s0, &c0);
    sincosf(0.5f*p1, &s1, &c1);
    sincosf(0.5f*p2, &s2, &c2);
    // U = RY(p2) * RX(p1) * RZ(p0)
    f2 e0  = (f2){c0, -s0};
    f2 e0c = (f2){c0,  s0};
    f2 is1 = (f2){0.f, -s1};
    f2 m00 = c1 * e0;
    f2 m01 = cmul(is1, e0c);
    f2 m10 = cmul(is1, e0);
    f2 m11 = c1 * e0c;
    f2 u00 = c2*m00 - s2*m10;
    f2 u01 = c2*m01 - s2*m11;
    f2 u10 = s2*m00 + c2*m10;
    f2 u11 = s2*m01 + c2*m11;
    if (d == 0) {
        G0[ww*2 + 0] = (f4){u00.x, u00.y, u01.x, u01.y};
        G0[ww*2 + 1] = (f4){u10.x, u10.y, u11.x, u11.y};
        return;
    }
    // half-layers h0..h5 = (1,A),(1,B),(2,B),(2,A),(3,A),(3,B);
    // slots: A: q0,q1,q2,q3,q6,q8,q9   B: q10,q11,q12,q13,q4,q5,q7
    const bool isA = (ww <= 3) || (ww == 6) || (ww == 8) || (ww == 9);
    int slot;
    if (isA) slot = (ww <= 3) ? ww : (ww == 6 ? 4 : (ww == 8 ? 5 : 6));
    else     slot = (ww >= 10) ? (ww - 10) : (ww == 4 ? 4 : (ww == 5 ? 5 : 6));
    const int h = (d == 1) ? (isA ? 0 : 1)
                : (d == 2) ? (isA ? 3 : 2)
                           : (isA ? 4 : 5);
    int* g = Gh + (h*7 + slot)*12;
    if (slot == 3) {   // within-pair gate: column packing A=(u00,u11) B=(u01,u10)
        g[0] = packh2(u00.x,  u11.x);
        g[1] = packh2(u00.y,  u11.y);
        g[2] = packh2(-u00.y, -u11.y);
        g[3] = packh2(u01.x,  u10.x);
        g[4] = packh2(u01.y,  u10.y);
        g[5] = packh2(-u01.y, -u10.y);
        #pragma unroll
        for (int k = 6; k < 12; ++k) g[k] = 0;
    } else {           // broadcast packing, rows with pre-negated imag
        g[0]  = packh2(u00.x,  u00.x);
        g[1]  = packh2(u00.y,  u00.y);
        g[2]  = packh2(-u00.y, -u00.y);
        g[3]  = packh2(u01.x,  u01.x);
        g[4]  = packh2(u01.y,  u01.y);
        g[5]  = packh2(-u01.y, -u01.y);
        g[6]  = packh2(u10.x,  u10.x);
        g[7]  = packh2(u10.y,  u10.y);
        g[8]  = packh2(-u10.y, -u10.y);
        g[9]  = packh2(u11.x,  u11.x);
        g[10] = packh2(u11.y,  u11.y);
        g[11] = packh2(-u11.y, -u11.y);
    }
}

__global__ __launch_bounds__(1024)
void qlg_kernel(const float* __restrict__ cond,
                const float* __restrict__ Wenc,
                const float* __restrict__ benc,
                const int* __restrict__ Gh,
                const f4* __restrict__ G0,
                float* __restrict__ out)
{
    __shared__ int st[DIM];                 // 64 KB remap buffer (packed f16 amps)
    __shared__ f2 qv[NQ][2];
    __shared__ f2 Phi[128];
    __shared__ f2 Plo[128];
    __shared__ float wred[16][NQ];
    __shared__ float lat[NQ];

    const int b = blockIdx.x;
    const int t = threadIdx.x;
    const int n = t & 63, w = t >> 6;
    const int bB = (w << 10)
                 | (((n >> 3) & 1) << 5) | (((n >> 1) & 1) << 4)
                 | (((n >> 5) & 1) << 3) | ((n & 1) << 2)
                 | (((n >> 4) & 1) << 1) | ((n >> 2) & 1);

    // ---- stage 1+2 merged: embedding (SiLU) + per-wire 2-vectors ----
    if (t < NQ) {
        float s = benc[t];
        #pragma unroll
        for (int k = 0; k < NQ; ++k) s += cond[b*NQ + k] * Wenc[t*NQ + k];
        float v = s / (1.0f + __expf(-s));
        float sn, cs;
        sincosf(0.5f*v, &sn, &cs);
        f2 a0 = (f2){cs*cs,  sn*sn};
        f2 a1 = (f2){sn*cs, -sn*cs};
        f4 va = G0[t*2], vb = G0[t*2 + 1];
        f2 u00 = (f2){va.x, va.y}, u01 = (f2){va.z, va.w};
        f2 u10 = (f2){vb.x, vb.y}, u11 = (f2){vb.z, vb.w};
        qv[t][0] = cmul(u00, a0) + cmul(u01, a1);
        qv[t][1] = cmul(u10, a0) + cmul(u11, a1);
    }
    __syncthreads();

    // ---- stage 3: partial-product tables (fp32) ----
    if (t < 128) {
        f2 p = qv[0][(t >> 6) & 1];
        #pragma unroll
        for (int ww = 1; ww <= 6; ++ww) p = cmul(p, qv[ww][(t >> (6 - ww)) & 1]);
        Phi[t] = p;
    } else if (t < 256) {
        const int j = t - 128;
        f2 p = qv[7][(j >> 6) & 1];
        #pragma unroll
        for (int ww = 8; ww <= 13; ++ww) p = cmul(p, qv[ww][(j >> (13 - ww)) & 1]);
        Plo[j] = p;
    }
    __syncthreads();

    // ---- stage 4: build product state in f16 planes (view A), CZ0 fused ----
    int hr[8], hi[8];
    {
        f2 plo = Plo[((n & 7) << 4) | w];
        #pragma unroll
        for (int k = 0; k < 8; ++k) {
            const int l0 = 2*k, l1 = 2*k + 1;
            const int e0 = (l0 << 10) | (n << 4) | w;
            const int e1 = (l1 << 10) | (n << 4) | w;
            f2 a0 = cmul(Phi[(l0 << 3) | (n >> 3)], plo) * czsgn(e0);
            f2 a1 = cmul(Phi[(l1 << 3) | (n >> 3)], plo) * czsgn(e1);
            hr[k] = packh2(a0.x, a1.x);
            hi[k] = packh2(a0.y, a1.y);
        }
    }

    // ---- stage 5: 6 half-layers ----
    #pragma unroll
    for (int h = 0; h < 6; ++h) {
        const int* __restrict__ g = Gh + h*7*12;
        reg_gate_h<4>(hr, hi, g + 0*12);    // l-mask 8
        reg_gate_h<2>(hr, hi, g + 1*12);    // l-mask 4
        reg_gate_h<1>(hr, hi, g + 2*12);    // l-mask 2
        pair_gate_h(hr, hi, g + 3*12);      // l-mask 1
        lane_gate_h<8>(hr, hi, g + 4*12, t);
        lane_gate_h<2>(hr, hi, g + 5*12, t);
        lane_gate_h<1>(hr, hi, g + 6*12, t);
        if (h == 1)      cz_B_h(hr, hi, t); // CZ after layer 1 (view B)
        else if (h == 3) cz_A_h(hr, hi, t); // CZ after layer 2 (view A)
        if (h == 0 || h == 4) {             // remap A -> B
            #pragma unroll
            for (int k = 0; k < 8; ++k) {
                st[t + ((2*k)   << 10)] = (hr[k] & 0xFFFF) | (hi[k] << 16);
                st[t + ((2*k+1) << 10)] = ((unsigned)hr[k] >> 16) | (hi[k] & 0xFFFF0000);
            }
            __syncthreads();
            #pragma unroll
            for (int k = 0; k < 8; ++k) {
                int w0 = st[bB + ((2*k)   << 6)];
                int w1 = st[bB + ((2*k+1) << 6)];
                hr[k] = (w0 & 0xFFFF) | (w1 << 16);
                hi[k] = ((unsigned)w0 >> 16) | (w1 & 0xFFFF0000);
            }
        } else if (h == 2) {                // remap B -> A
            #pragma unroll
            for (int k = 0; k < 8; ++k) {
                st[bB + ((2*k)   << 6)] = (hr[k] & 0xFFFF) | (hi[k] << 16);
                st[bB + ((2*k+1) << 6)] = ((unsigned)hr[k] >> 16) | (hi[k] & 0xFFFF0000);
            }
            __syncthreads();
            #pragma unroll
            for (int k = 0; k < 8; ++k) {
                int w0 = st[t + ((2*k)   << 10)];
                int w1 = st[t + ((2*k+1) << 10)];
                hr[k] = (w0 & 0xFFFF) | (w1 << 16);
                hi[k] = ((unsigned)w0 >> 16) | (w1 & 0xFFFF0000);
            }
        }
    }
    // (CZ after layer 3 dropped: |psi|^2 invariant)

    // ---- fused probability reduction (view B, fp32 accumulate) ----
    float SU, Q10, Q11, Q12, Q13;
    {
        SU = Q10 = Q11 = Q12 = Q13 = 0.f;
        #pragma unroll
        for (int k = 0; k < 8; ++k) {
            union { int i; __half2 h; } ur, ui;
            ur.i = hr[k]; ui.i = hi[k];
            float2 fr = __half22float2(ur.h);
            float2 fi = __half22float2(ui.h);
            float pl = fr.x*fr.x + fi.x*fi.x;
            float ph = fr.y*fr.y + fi.y*fi.y;
            float g2 = pl + ph;
            SU  += g2;
            Q13 += pl - ph;                 // l0
            Q10 += (k & 4) ? -g2 : g2;      // l3
            Q11 += (k & 2) ? -g2 : g2;      // l2
            Q12 += (k & 1) ? -g2 : g2;      // l1
        }
    }

    // ---- stage 6: reduce to 14 expectations, layernorm (fp32) ----
    // View-B thread-uniform sign bits: q0:t9 q1:t8 q2:t7 q3:t6 q4:t3 q5:t1
    // q6:t5 q7:t0 q8:t4 q9:t2.
    {
        const int lane = t & 63, wv = t >> 6;
        const int sbit[10] = {9, 8, 7, 6, 3, 1, 5, 0, 4, 2};
        #pragma unroll
        for (int ww = 0; ww < NQ; ++ww) {
            float v;
            if      (ww == 10) v = Q10;
            else if (ww == 11) v = Q11;
            else if (ww == 12) v = Q12;
            else if (ww == 13) v = Q13;
            else               v = ((t >> sbit[ww]) & 1) ? -SU : SU;
            #pragma unroll
            for (int off = 32; off > 0; off >>= 1) v += __shfl_down(v, off, 64);
            if (lane == 0) wred[wv][ww] = v;
        }
    }
    __syncthreads();
    if (t < NQ) {
        float s = 0.f;
        #pragma unroll
        for (int k = 0; k < 16; ++k) s += wred[k][t];
        lat[t] = s;
    }
    __syncthreads();
    if (t < NQ) {
        float mu = 0.f;
        #pragma unroll
        for (int k = 0; k < NQ; ++k) mu += lat[k];
        mu *= (1.0f / NQ);
        float var = 0.f;
        #pragma unroll
        for (int k = 0; k < NQ; ++k) { float dv = lat[k] - mu; var += dv*dv; }
        var *= (1.0f / NQ);
        out[b*NQ + t] = (lat[t] - mu) * rsqrtf(var + 1e-5f);
    }
}

extern "C" void kernel_launch(void* const* d_in, const int* in_sizes, int n_in,
                              void* d_out, int out_size, void* d_ws, size_t ws_size,
                              hipStream_t stream)
{
    (void)n_in; (void)ws_size; (void)out_size;
    const float* cond = (const float*)d_in[0];
    const float* Wenc = (const float*)d_in[1];
    const float* benc = (const float*)d_in[2];
    const float* wts  = (const float*)d_in[3];
    float* out = (float*)d_out;
    int* Gh = (int*)d_ws;                        // 504 ints = 2016 B
    f4* G0 = (f4*)((char*)d_ws + 4096);          // 28 f4 = 448 B
    const int B = in_sizes[0] / NQ;              // 256
    qlg_prep<<<dim3(1), dim3(64), 0, stream>>>(wts, Gh, G0);
    qlg_kernel<<<dim3(B), dim3(1024), 0, stream>>>(cond, Wenc, benc, Gh, G0, out);
}